// Round 2
// baseline (266.916 us; speedup 1.0000x reference)
//
#include <hip/hip_runtime.h>
#include <math.h>

// out[h, i, j] = scores[h, S-1 + i - j]  -- each output row is a contiguous,
// order-preserving window of the REVERSED score vector:
//   rev_h[t] = scores[h][2S-2 - t]  =>  out[h][i][j] = rev_h[(S-1-i) + j].
//
// Round-3 change: the previous fused kernel's store stream ran at ~2.7 TB/s
// (vs 6.6 TB/s the harness fill proves the same buffer sustains). Issue-side
// arithmetic (~1.5 us/SIMD) and the round-1->2 null result rule out VALU and
// LDS latency; the structure itself (reversal movs fused in the store loop,
// LDS interlock, 4 blocks/CU) throttles the drain. New plan: make the big
// kernel a pure memcpy. Kernel 1 builds FOUR shift-copies of rev per head
// (T[h][c][t] = scores[2S-2-t-c], ~1 MiB in d_ws) so that for every row i
// the source pointer (base = S-1-i, pick copy c = base&3) is 16B-aligned.
// Kernel 2 is then aligned float4 L2-loads + aligned float4 stores, no LDS,
// no barriers, no register shuffles -- structurally identical to the fill.

#define BLOCK 256
#define TI 32   // fallback kernel's rows-per-block

// ---------- Kernel 1: shifted reversed score tables (tiny) ----------
__global__ __launch_bounds__(BLOCK) void build_tables_kernel(
    const float* __restrict__ koff, const float* __restrict__ kwid,
    const float* __restrict__ kamp, float* __restrict__ tbl,
    int S, int H, int K, int tstride) {
  const int c = blockIdx.x;   // shift 0..3
  const int h = blockIdx.y;

  float o0=0,o1=0,o2=0,o3=0,o4=0, w0=0,w1=0,w2=0,w3=0,w4=0, a0=0,a1=0,a2=0,a3=0,a4=0;
  if (K > 0) { o0=koff[0*H+h]; w0=fabsf(kwid[0*H+h]); a0=kamp[0*H+h]; }
  if (K > 1) { o1=koff[1*H+h]; w1=fabsf(kwid[1*H+h]); a1=kamp[1*H+h]; }
  if (K > 2) { o2=koff[2*H+h]; w2=fabsf(kwid[2*H+h]); a2=kamp[2*H+h]; }
  if (K > 3) { o3=koff[3*H+h]; w3=fabsf(kwid[3*H+h]); a3=kamp[3*H+h]; }
  if (K > 4) { o4=koff[4*H+h]; w4=fabsf(kwid[4*H+h]); a4=kamp[4*H+h]; }

  float* __restrict__ dst = tbl + ((size_t)h * 4 + c) * (size_t)tstride;
  const int n = 2 * S - 1;
  for (int t = threadIdx.x; t < n; t += BLOCK) {
    int idx = 2 * S - 2 - t - c;          // reversed + shifted
    if (idx < 0) continue;                // never read by kernel 2
    float rel = (float)(idx - S);
    float d0 = o0 - rel, d1 = o1 - rel, d2 = o2 - rel, d3 = o3 - rel, d4 = o4 - rel;
    dst[t] = a0 * __expf(-w0 * d0 * d0)
           + a1 * __expf(-w1 * d1 * d1)
           + a2 * __expf(-w2 * d2 * d2)
           + a3 * __expf(-w3 * d3 * d3)
           + a4 * __expf(-w4 * d4 * d4);
  }
}

// ---------- Kernel 2: pure row-copy streamer (the 256 MiB) ----------
// Per row i: base = S-1-i, c = base&3, T_c[base-c + j] == rev[base + j],
// and (base-c), j are both multiples of 4 -> aligned float4 both sides.
__global__ __launch_bounds__(BLOCK) void row_copy_kernel(
    const float* __restrict__ tbl, float* __restrict__ out,
    int S, int tstride) {
  const int h = blockIdx.y;
  for (int i = blockIdx.x; i < S; i += gridDim.x) {
    const int base = S - 1 - i;
    const int c = base & 3;
    const float* __restrict__ src =
        tbl + ((size_t)h * 4 + c) * (size_t)tstride + (base - c);
    float* __restrict__ dst = out + ((size_t)h * S + i) * (size_t)S;
    for (int j = threadIdx.x * 4; j < S; j += BLOCK * 4) {
      *(float4*)(dst + j) = *(const float4*)(src + j);   // L2 hit -> HBM store
    }
  }
}

// ---------- Fallback: round-2 fused kernel (any S, no workspace) ----------
__global__ __launch_bounds__(BLOCK) void toeplitz_rbf_kernel(
    const float* __restrict__ koff, const float* __restrict__ kwid,
    const float* __restrict__ kamp, float* __restrict__ out,
    int S, int H, int K) {
  extern __shared__ float lds[];
  const int h  = blockIdx.y;
  const int i0 = blockIdx.x * TI;
  const int nscore = S + TI - 1;

  float o0=0,o1=0,o2=0,o3=0,o4=0, w0=0,w1=0,w2=0,w3=0,w4=0, a0=0,a1=0,a2=0,a3=0,a4=0;
  if (K > 0) { o0=koff[0*H+h]; w0=fabsf(kwid[0*H+h]); a0=kamp[0*H+h]; }
  if (K > 1) { o1=koff[1*H+h]; w1=fabsf(kwid[1*H+h]); a1=kamp[1*H+h]; }
  if (K > 2) { o2=koff[2*H+h]; w2=fabsf(kwid[2*H+h]); a2=kamp[2*H+h]; }
  if (K > 3) { o3=koff[3*H+h]; w3=fabsf(kwid[3*H+h]); a3=kamp[3*H+h]; }
  if (K > 4) { o4=koff[4*H+h]; w4=fabsf(kwid[4*H+h]); a4=kamp[4*H+h]; }

  for (int t = threadIdx.x; t < nscore; t += BLOCK) {
    float rel = (float)(i0 + t - S);
    float d0 = o0 - rel, d1 = o1 - rel, d2 = o2 - rel, d3 = o3 - rel, d4 = o4 - rel;
    lds[t] = a0 * __expf(-w0 * d0 * d0)
           + a1 * __expf(-w1 * d1 * d1)
           + a2 * __expf(-w2 * d2 * d2)
           + a3 * __expf(-w3 * d3 * d3)
           + a4 * __expf(-w4 * d4 * d4);
  }
  __syncthreads();

  const int rows = (S - i0 < TI) ? (S - i0) : TI;
  if (rows == TI && (S & 3) == 0) {
    for (int j = threadIdx.x * 4; j < S; j += BLOCK * 4) {
      const int t0 = S - 1 - j;
      float w[TI + 4];
      #pragma unroll
      for (int m = 0; m < (TI + 4) / 4; ++m)
        *(float4*)&w[4 * m] = *(const float4*)&lds[(t0 - 3) + 4 * m];
      float* __restrict__ p = out + ((size_t)h * S + i0) * (size_t)S + j;
      #pragma unroll
      for (int di = 0; di < TI; ++di) {
        *(float4*)p = make_float4(w[di + 3], w[di + 2], w[di + 1], w[di]);
        p += S;
      }
    }
  } else {
    for (int idx = threadIdx.x; idx < rows * S; idx += BLOCK) {
      int di = idx / S;
      int j  = idx - di * S;
      out[((size_t)h * S + (size_t)(i0 + di)) * (size_t)S + j] =
          lds[(S - 1) + di - j];
    }
  }
}

extern "C" void kernel_launch(void* const* d_in, const int* in_sizes, int n_in,
                              void* d_out, int out_size, void* d_ws, size_t ws_size,
                              hipStream_t stream) {
  const float* koff = (const float*)d_in[1];
  const float* kwid = (const float*)d_in[2];
  const float* kamp = (const float*)d_in[3];
  float* out = (float*)d_out;

  const int K = 5;
  int H = (n_in > 1 && in_sizes[1] > 0) ? in_sizes[1] / K : 16;
  if (H <= 0) H = 16;
  long long ss = (long long)out_size / H;     // S*S
  int S = (int)(sqrt((double)ss) + 0.5);

  // Table stride in floats: >= 2S-1, multiple of 4 (keeps each table 16B-aligned).
  const int tstride = (2 * S + 8) & ~3;
  const size_t ws_needed = (size_t)H * 4 * (size_t)tstride * sizeof(float);

  if ((S & 3) == 0 && d_ws != nullptr && ws_size >= ws_needed) {
    // Two-kernel path: tiny table build, then pure streamer.
    dim3 g1(4, H);
    build_tables_kernel<<<g1, BLOCK, 0, stream>>>(koff, kwid, kamp,
                                                  (float*)d_ws, S, H, K, tstride);
    int gx = (S >= 512) ? 512 : S;            // 512x16 blocks, 4 rows each @ S=2048
    dim3 g2(gx, H);
    row_copy_kernel<<<g2, BLOCK, 0, stream>>>((const float*)d_ws, out, S, tstride);
  } else {
    dim3 grid((S + TI - 1) / TI, H);
    size_t lds_bytes = (size_t)(S + TI) * sizeof(float);
    toeplitz_rbf_kernel<<<grid, BLOCK, lds_bytes, stream>>>(koff, kwid, kamp, out, S, H, K);
  }
}